// Round 1
// baseline (752.772 us; speedup 1.0000x reference)
//
#include <hip/hip_runtime.h>
#include <math.h>

#define D 128
#define ROWS 32
#define WPAD 129  // 129 mod 32 == 1 -> column reads spread across banks

// ---------------- degree ----------------
__global__ __launch_bounds__(256) void k_deg(const int* __restrict__ src,
                                             const int* __restrict__ dst,
                                             float* __restrict__ deg, int E) {
  int e = blockIdx.x * 256 + threadIdx.x;
  if (e < E) {
    atomicAdd(&deg[src[e]], 1.0f);
    atomicAdd(&deg[dst[e]], 1.0f);
  }
}

__global__ __launch_bounds__(256) void k_dinv(const float* __restrict__ deg,
                                              float* __restrict__ dinv, int N) {
  int i = blockIdx.x * 256 + threadIdx.x;
  if (i < N) dinv[i] = rsqrtf(fmaxf(deg[i], 1.0f));
}

// ---------------- fused logmap0 + GEMM (h = logmap0(x) @ W^T + b) ----------------
__global__ __launch_bounds__(256) void k_logmap_gemm(
    const float* __restrict__ x, const float* __restrict__ W,
    const float* __restrict__ b, float* __restrict__ h, int N) {
  __shared__ float Ws[D * WPAD];     // row-major [j][k], padded
  __shared__ float xs[ROWS * D];     // x tile, scaled in place by logmap factor
  __shared__ float part[ROWS * 8];
  __shared__ float rscale[ROWS];
  __shared__ float bs[D];

  const int t = threadIdx.x;
  const int r0 = blockIdx.x * ROWS;

  // stage W (coalesced global read; LDS write conflict-free: consecutive k)
  for (int i = t; i < D * D; i += 256) {
    int j = i >> 7, k = i & 127;
    Ws[j * WPAD + k] = W[i];
  }
  if (t < D) bs[t] = b[t];

  // stage x tile (guarded, zero-fill past N)
  for (int i = t; i < ROWS * D; i += 256) {
    int gr = r0 + (i >> 7);
    xs[i] = (gr < N) ? x[(size_t)gr * D + (i & 127)] : 0.0f;
  }
  __syncthreads();

  // per-row sum of squares: 8 threads/row x 16 elems
  {
    int r = t >> 3, c0 = (t & 7) * 16;
    float s = 0.0f;
#pragma unroll
    for (int k = 0; k < 16; ++k) {
      float v = xs[r * D + c0 + k];
      s += v * v;
    }
    part[t] = s;
  }
  __syncthreads();
  if (t < ROWS) {
    float s = 0.0f;
#pragma unroll
    for (int k = 0; k < 8; ++k) s += part[t * 8 + k];
    float nrm = sqrtf(s);
    float nc = fminf(fmaxf(nrm, 1e-15f), 1.0f - 1e-5f);
    rscale[t] = atanhf(nc) / fmaxf(nrm, 1e-15f);
  }
  __syncthreads();
  // scale xs in place (16 consecutive elems per thread = single row)
  {
    int i0 = t * 16;
    float sc = rscale[i0 >> 7];
#pragma unroll
    for (int k = 0; k < 16; ++k) xs[i0 + k] *= sc;
  }
  __syncthreads();

  // compute: each thread -> 4 rows x 4 cols (col stride 32 -> conflict-free Ws reads)
  const int jj = t & 31;
  const int rr = (t >> 5) * 4;
  float acc[4][4];
#pragma unroll
  for (int a = 0; a < 4; ++a)
#pragma unroll
    for (int c = 0; c < 4; ++c) acc[a][c] = 0.0f;

  for (int k = 0; k < D; ++k) {
    float w0 = Ws[(jj)*WPAD + k];
    float w1 = Ws[(jj + 32) * WPAD + k];
    float w2 = Ws[(jj + 64) * WPAD + k];
    float w3 = Ws[(jj + 96) * WPAD + k];
#pragma unroll
    for (int a = 0; a < 4; ++a) {
      float xv = xs[(rr + a) * D + k];
      acc[a][0] += xv * w0;
      acc[a][1] += xv * w1;
      acc[a][2] += xv * w2;
      acc[a][3] += xv * w3;
    }
  }

#pragma unroll
  for (int a = 0; a < 4; ++a) {
    int gr = r0 + rr + a;
    if (gr < N) {
      float* hp = h + (size_t)gr * D;
#pragma unroll
      for (int c = 0; c < 4; ++c) hp[jj + 32 * c] = acc[a][c] + bs[jj + 32 * c];
    }
  }
}

// ---------------- gather-scale-scatter (one wave per edge) ----------------
__global__ __launch_bounds__(256) void k_scatter(
    const float* __restrict__ h, const int* __restrict__ src,
    const int* __restrict__ dst, const float* __restrict__ dinv,
    float* __restrict__ out, int E) {
  int gid = blockIdx.x * 256 + threadIdx.x;
  int e = gid >> 6, lane = gid & 63;
  if (e >= E) return;
  int s = src[e], d = dst[e];
  float w = dinv[s] * dinv[d];
  const float2* hp = (const float2*)(h + (size_t)s * D);
  float2 v = hp[lane];
  float* op = out + (size_t)d * D + lane * 2;
  atomicAdd(op, v.x * w);
  atomicAdd(op + 1, v.y * w);
}

// ---------------- expmap0 in place (one wave per row) ----------------
__global__ __launch_bounds__(256) void k_expmap(float* __restrict__ out, int N) {
  int gid = blockIdx.x * 256 + threadIdx.x;
  int r = gid >> 6, lane = gid & 63;
  if (r >= N) return;
  float2* p = (float2*)(out + (size_t)r * D);
  float2 v = p[lane];
  float ss = v.x * v.x + v.y * v.y;
#pragma unroll
  for (int off = 32; off > 0; off >>= 1) ss += __shfl_down(ss, off);
  ss = __shfl(ss, 0);
  float n = sqrtf(ss);
  float sc = tanhf(n) / fmaxf(n, 1e-15f);
  v.x *= sc;
  v.y *= sc;
  p[lane] = v;
}

extern "C" void kernel_launch(void* const* d_in, const int* in_sizes, int n_in,
                              void* d_out, int out_size, void* d_ws, size_t ws_size,
                              hipStream_t stream) {
  const float* x = (const float*)d_in[0];
  const int* ei = (const int*)d_in[1];
  const float* W = (const float*)d_in[2];
  const float* b = (const float*)d_in[3];
  float* out = (float*)d_out;

  const int N = in_sizes[0] / D;
  const int E = in_sizes[1] / 2;
  const int* src = ei;
  const int* dst = ei + E;

  float* h = (float*)d_ws;               // N*D floats
  float* deg = h + (size_t)N * D;        // N floats
  float* dinv = deg + N;                 // N floats

  hipMemsetAsync(deg, 0, (size_t)N * sizeof(float), stream);
  hipMemsetAsync(d_out, 0, (size_t)out_size * sizeof(float), stream);

  k_deg<<<(E + 255) / 256, 256, 0, stream>>>(src, dst, deg, E);
  k_dinv<<<(N + 255) / 256, 256, 0, stream>>>(deg, dinv, N);
  k_logmap_gemm<<<(N + ROWS - 1) / ROWS, 256, 0, stream>>>(x, W, b, h, N);
  k_scatter<<<(int)(((long long)E * 64 + 255) / 256), 256, 0, stream>>>(h, src, dst, dinv, out, E);
  k_expmap<<<(int)(((long long)N * 64 + 255) / 256), 256, 0, stream>>>(out, N);
}

// Round 2
// 351.520 us; speedup vs baseline: 2.1415x; 2.1415x over previous
//
#include <hip/hip_runtime.h>
#include <math.h>

#define D 128
#define ROWS 32
#define WPAD 129

// ---------------- histograms: cnt[dst]++, cnts[src]++ ----------------
__global__ __launch_bounds__(256) void k_hist(const int* __restrict__ src,
                                              const int* __restrict__ dst,
                                              int* __restrict__ cnt,
                                              int* __restrict__ cnts, int E) {
  int e = blockIdx.x * 256 + threadIdx.x;
  if (e < E) {
    atomicAdd(&cnt[dst[e]], 1);
    atomicAdd(&cnts[src[e]], 1);
  }
}

__global__ __launch_bounds__(256) void k_dinv(const int* __restrict__ cnt,
                                              const int* __restrict__ cnts,
                                              float* __restrict__ dinv, int N) {
  int i = blockIdx.x * 256 + threadIdx.x;
  if (i < N) dinv[i] = rsqrtf(fmaxf((float)(cnt[i] + cnts[i]), 1.0f));
}

// ---------------- exclusive scan of cnt -> offs (3 kernels) ----------------
__global__ __launch_bounds__(256) void k_scan1(const int* __restrict__ cnt,
                                               int* __restrict__ offs,
                                               int* __restrict__ bsum, int N) {
  __shared__ int s[256];
  int t = threadIdx.x;
  int i = blockIdx.x * 256 + t;
  int v = (i < N) ? cnt[i] : 0;
  s[t] = v;
  __syncthreads();
  // Hillis-Steele inclusive scan
  for (int off = 1; off < 256; off <<= 1) {
    int a = (t >= off) ? s[t - off] : 0;
    __syncthreads();
    s[t] += a;
    __syncthreads();
  }
  if (i < N) offs[i] = s[t] - v;  // exclusive
  if (t == 255) bsum[blockIdx.x] = s[255];
}

__global__ void k_scan2(int* __restrict__ bsum, int nb) {
  // single thread: exclusive scan of block sums (nb ~ 196)
  int run = 0;
  for (int i = 0; i < nb; ++i) {
    int v = bsum[i];
    bsum[i] = run;
    run += v;
  }
}

__global__ __launch_bounds__(256) void k_scan3(int* __restrict__ offs,
                                               const int* __restrict__ bsum,
                                               int N, int E) {
  int i = blockIdx.x * 256 + threadIdx.x;
  if (i < N) offs[i] += bsum[i >> 8];
  if (i == N) offs[N] = E;
}

// ---------------- bucket edges by dst ----------------
__global__ __launch_bounds__(256) void k_fill(const int* __restrict__ src,
                                              const int* __restrict__ dst,
                                              const int* __restrict__ offs,
                                              int* __restrict__ cursor,
                                              int* __restrict__ ebuf, int E) {
  int e = blockIdx.x * 256 + threadIdx.x;
  if (e < E) {
    int d = dst[e];
    int pos = offs[d] + atomicAdd(&cursor[d], 1);
    ebuf[pos] = src[e];
  }
}

// ---------------- fused logmap0 + GEMM (h = logmap0(x) @ W^T + b) ----------------
__global__ __launch_bounds__(256) void k_logmap_gemm(
    const float* __restrict__ x, const float* __restrict__ W,
    const float* __restrict__ b, float* __restrict__ h, int N) {
  __shared__ float Ws[D * WPAD];
  __shared__ float xs[ROWS * D];
  __shared__ float part[ROWS * 8];
  __shared__ float rscale[ROWS];
  __shared__ float bs[D];

  const int t = threadIdx.x;
  const int r0 = blockIdx.x * ROWS;

  for (int i = t; i < D * D; i += 256) {
    int j = i >> 7, k = i & 127;
    Ws[j * WPAD + k] = W[i];
  }
  if (t < D) bs[t] = b[t];

  for (int i = t; i < ROWS * D; i += 256) {
    int gr = r0 + (i >> 7);
    xs[i] = (gr < N) ? x[(size_t)gr * D + (i & 127)] : 0.0f;
  }
  __syncthreads();

  {
    int r = t >> 3, c0 = (t & 7) * 16;
    float s = 0.0f;
#pragma unroll
    for (int k = 0; k < 16; ++k) {
      float v = xs[r * D + c0 + k];
      s += v * v;
    }
    part[t] = s;
  }
  __syncthreads();
  if (t < ROWS) {
    float s = 0.0f;
#pragma unroll
    for (int k = 0; k < 8; ++k) s += part[t * 8 + k];
    float nrm = sqrtf(s);
    float nc = fminf(fmaxf(nrm, 1e-15f), 1.0f - 1e-5f);
    rscale[t] = atanhf(nc) / fmaxf(nrm, 1e-15f);
  }
  __syncthreads();
  {
    int i0 = t * 16;
    float sc = rscale[i0 >> 7];
#pragma unroll
    for (int k = 0; k < 16; ++k) xs[i0 + k] *= sc;
  }
  __syncthreads();

  const int jj = t & 31;
  const int rr = (t >> 5) * 4;
  float acc[4][4];
#pragma unroll
  for (int a = 0; a < 4; ++a)
#pragma unroll
    for (int c = 0; c < 4; ++c) acc[a][c] = 0.0f;

  for (int k = 0; k < D; ++k) {
    float w0 = Ws[(jj)*WPAD + k];
    float w1 = Ws[(jj + 32) * WPAD + k];
    float w2 = Ws[(jj + 64) * WPAD + k];
    float w3 = Ws[(jj + 96) * WPAD + k];
#pragma unroll
    for (int a = 0; a < 4; ++a) {
      float xv = xs[(rr + a) * D + k];
      acc[a][0] += xv * w0;
      acc[a][1] += xv * w1;
      acc[a][2] += xv * w2;
      acc[a][3] += xv * w3;
    }
  }

#pragma unroll
  for (int a = 0; a < 4; ++a) {
    int gr = r0 + rr + a;
    if (gr < N) {
      float* hp = h + (size_t)gr * D;
#pragma unroll
      for (int c = 0; c < 4; ++c) hp[jj + 32 * c] = acc[a][c] + bs[jj + 32 * c];
    }
  }
}

// ---------------- gather + expmap0 fused (one wave per dst node) ----------------
__global__ __launch_bounds__(256) void k_gather_expmap(
    const float* __restrict__ h, const int* __restrict__ ebuf,
    const int* __restrict__ offs, const float* __restrict__ dinv,
    float* __restrict__ out, int N) {
  int gid = blockIdx.x * 256 + threadIdx.x;
  int r = gid >> 6, lane = gid & 63;
  if (r >= N) return;

  int start = offs[r], end = offs[r + 1];
  float di_d = dinv[r];
  float ax = 0.0f, ay = 0.0f;

  for (int i = start; i < end; ++i) {
    int s = ebuf[i];                 // wave-uniform
    float w = di_d * dinv[s];
    const float2* hp = (const float2*)(h + (size_t)s * D);
    float2 v = hp[lane];             // coalesced 512B per wave
    ax += w * v.x;
    ay += w * v.y;
  }

  // expmap0: norm over the 128-dim row held as 2 floats/lane
  float ss = ax * ax + ay * ay;
#pragma unroll
  for (int off = 32; off > 0; off >>= 1) ss += __shfl_down(ss, off);
  ss = __shfl(ss, 0);
  float n = sqrtf(ss);
  float sc = tanhf(n) / fmaxf(n, 1e-15f);

  float2* op = (float2*)(out + (size_t)r * D);
  float2 o;
  o.x = ax * sc;
  o.y = ay * sc;
  op[lane] = o;
}

extern "C" void kernel_launch(void* const* d_in, const int* in_sizes, int n_in,
                              void* d_out, int out_size, void* d_ws, size_t ws_size,
                              hipStream_t stream) {
  const float* x = (const float*)d_in[0];
  const int* ei = (const int*)d_in[1];
  const float* W = (const float*)d_in[2];
  const float* b = (const float*)d_in[3];
  float* out = (float*)d_out;

  const int N = in_sizes[0] / D;
  const int E = in_sizes[1] / 2;
  const int* src = ei;
  const int* dst = ei + E;

  // workspace layout
  float* h = (float*)d_ws;                 // N*D floats
  float* dinv = h + (size_t)N * D;         // N floats
  int* cnt = (int*)(dinv + N);             // N ints (dst histogram)
  int* cnts = cnt + N;                     // N ints (src histogram; later cursor)
  int* offs = cnts + N;                    // N+1 ints
  int* bsum = offs + N + 1;                // 256 ints
  int* ebuf = bsum + 256;                  // E ints

  const int nb = (N + 255) / 256;

  hipMemsetAsync(cnt, 0, (size_t)N * sizeof(int) * 2, stream);  // cnt + cnts

  k_hist<<<(E + 255) / 256, 256, 0, stream>>>(src, dst, cnt, cnts, E);
  k_dinv<<<nb, 256, 0, stream>>>(cnt, cnts, dinv, N);
  k_scan1<<<nb, 256, 0, stream>>>(cnt, offs, bsum, N);
  k_scan2<<<1, 1, 0, stream>>>(bsum, nb);
  k_scan3<<<(N + 256) / 256, 256, 0, stream>>>(offs, bsum, N, E);

  hipMemsetAsync(cnts, 0, (size_t)N * sizeof(int), stream);  // cursor
  k_fill<<<(E + 255) / 256, 256, 0, stream>>>(src, dst, offs, cnts, ebuf, E);

  k_logmap_gemm<<<(N + ROWS - 1) / ROWS, 256, 0, stream>>>(x, W, b, h, N);

  k_gather_expmap<<<(int)(((long long)N * 64 + 255) / 256), 256, 0, stream>>>(
      h, ebuf, offs, dinv, out, N);
}

// Round 3
// 232.295 us; speedup vs baseline: 3.2406x; 1.5132x over previous
//
#include <hip/hip_runtime.h>
#include <math.h>

#define D 128

typedef __attribute__((ext_vector_type(8))) short short8;
typedef __attribute__((ext_vector_type(4))) float f32x4;

__device__ inline unsigned short f2bf(float f) {
  unsigned int u = __float_as_uint(f);
  u = (u + 0x7FFFu + ((u >> 16) & 1u)) >> 16;  // RNE
  return (unsigned short)u;
}
__device__ inline float bf2f(unsigned int us) {
  return __uint_as_float(us << 16);
}

// ---------------- histograms: cnt[dst]++, cnts[src]++ ----------------
__global__ __launch_bounds__(256) void k_hist(const int* __restrict__ src,
                                              const int* __restrict__ dst,
                                              int* __restrict__ cnt,
                                              int* __restrict__ cnts, int E) {
  int e = blockIdx.x * 256 + threadIdx.x;
  if (e < E) {
    atomicAdd(&cnt[dst[e]], 1);
    atomicAdd(&cnts[src[e]], 1);
  }
}

__global__ __launch_bounds__(256) void k_dinv(const int* __restrict__ cnt,
                                              const int* __restrict__ cnts,
                                              float* __restrict__ dinv, int N) {
  int i = blockIdx.x * 256 + threadIdx.x;
  if (i < N) dinv[i] = rsqrtf(fmaxf((float)(cnt[i] + cnts[i]), 1.0f));
}

// ---------------- exclusive scan of cnt -> offs ----------------
__global__ __launch_bounds__(256) void k_scan1(const int* __restrict__ cnt,
                                               int* __restrict__ offs,
                                               int* __restrict__ bsum, int N) {
  __shared__ int s[256];
  int t = threadIdx.x;
  int i = blockIdx.x * 256 + t;
  int v = (i < N) ? cnt[i] : 0;
  s[t] = v;
  __syncthreads();
  for (int off = 1; off < 256; off <<= 1) {
    int a = (t >= off) ? s[t - off] : 0;
    __syncthreads();
    s[t] += a;
    __syncthreads();
  }
  if (i < N) offs[i] = s[t] - v;  // exclusive
  if (t == 255) bsum[blockIdx.x] = s[255];
}

__global__ __launch_bounds__(256) void k_scan2(int* __restrict__ bsum, int nb) {
  // parallel exclusive scan of block sums (nb <= 256)
  __shared__ int s[256];
  int t = threadIdx.x;
  int v = (t < nb) ? bsum[t] : 0;
  s[t] = v;
  __syncthreads();
  for (int off = 1; off < 256; off <<= 1) {
    int a = (t >= off) ? s[t - off] : 0;
    __syncthreads();
    s[t] += a;
    __syncthreads();
  }
  if (t < nb) bsum[t] = s[t] - v;
}

__global__ __launch_bounds__(256) void k_scan3(int* __restrict__ offs,
                                               const int* __restrict__ bsum,
                                               int N, int E) {
  int i = blockIdx.x * 256 + threadIdx.x;
  if (i < N) offs[i] += bsum[i >> 8];
  if (i == N) offs[N] = E;
}

// ---------------- bucket edges by dst ----------------
__global__ __launch_bounds__(256) void k_fill(const int* __restrict__ src,
                                              const int* __restrict__ dst,
                                              const int* __restrict__ offs,
                                              int* __restrict__ cursor,
                                              int* __restrict__ ebuf, int E) {
  int e = blockIdx.x * 256 + threadIdx.x;
  if (e < E) {
    int d = dst[e];
    int pos = offs[d] + atomicAdd(&cursor[d], 1);
    ebuf[pos] = src[e];
  }
}

// ---------------- fused logmap0 + GEMM via bf16 MFMA ----------------
// h[r][j] = bf16( rscale[r] * (x[r] . W[j]) + b[j] )
// Block = 256 thr = 4 waves; each wave does a 16-row x 128-col tile; block = 64 rows.
__global__ __launch_bounds__(256) void k_gemm_mfma(
    const float* __restrict__ x, const float* __restrict__ W,
    const float* __restrict__ b, unsigned short* __restrict__ h, int N) {
  // W in LDS as bf16, chunk-major: [c16 (k-chunk of 8)][row j][8 elems]
  __shared__ unsigned short Wl[16 * 128 * 8];  // 32 KB
  __shared__ float bs[D];

  const int t = threadIdx.x;
  const int w = t >> 6;        // wave 0..3
  const int l = t & 63;        // lane
  const int lc = l & 15;       // lane&15
  const int q = l >> 4;        // quad 0..3
  const int r0 = blockIdx.x * 64;

  // stage W -> bf16 LDS (coalesced float4 reads)
  for (int i = t * 4; i < D * D; i += 1024) {
    float4 wv = *(const float4*)(W + i);
    int r = i >> 7, c = i & 127;
    int idx = ((c >> 3) << 10) + (r << 3) + (c & 7);
    unsigned short p0 = f2bf(wv.x), p1 = f2bf(wv.y), p2 = f2bf(wv.z), p3 = f2bf(wv.w);
    ushort4 pk = make_ushort4(p0, p1, p2, p3);
    *(ushort4*)(&Wl[idx]) = pk;
  }
  if (t < D) bs[t] = b[t];

  // A fragments direct from global (row = r0 + w*16 + lc), plus sum of squares
  const int grow = r0 + w * 16 + lc;
  const bool ok = grow < N;
  const float* xp = x + (size_t)grow * D + q * 8;

  short8 a[4];
  float ss = 0.0f;
#pragma unroll
  for (int kk = 0; kk < 4; ++kk) {
    float4 u = ok ? *(const float4*)(xp + kk * 32) : make_float4(0, 0, 0, 0);
    float4 v = ok ? *(const float4*)(xp + kk * 32 + 4) : make_float4(0, 0, 0, 0);
    ss += u.x * u.x + u.y * u.y + u.z * u.z + u.w * u.w;
    ss += v.x * v.x + v.y * v.y + v.z * v.z + v.w * v.w;
    short8 af;
    af[0] = (short)f2bf(u.x); af[1] = (short)f2bf(u.y);
    af[2] = (short)f2bf(u.z); af[3] = (short)f2bf(u.w);
    af[4] = (short)f2bf(v.x); af[5] = (short)f2bf(v.y);
    af[6] = (short)f2bf(v.z); af[7] = (short)f2bf(v.w);
    a[kk] = af;
  }
  // reduce partial sumsq across the 4 lanes sharing row lc (l, l^16, l^32, l^48)
  ss += __shfl_xor(ss, 16, 64);
  ss += __shfl_xor(ss, 32, 64);
  float nrm = sqrtf(ss);
  float nc = fminf(fmaxf(nrm, 1e-15f), 1.0f - 1e-5f);
  float rs = atanhf(nc) / fmaxf(nrm, 1e-15f);

  __syncthreads();

  // MFMA: 8 col-tiles x 4 k-steps
  f32x4 acc[8];
#pragma unroll
  for (int nt = 0; nt < 8; ++nt) acc[nt] = (f32x4){0.f, 0.f, 0.f, 0.f};

#pragma unroll
  for (int kk = 0; kk < 4; ++kk) {
#pragma unroll
    for (int nt = 0; nt < 8; ++nt) {
      short8 bf = *(const short8*)(&Wl[((kk * 4 + q) << 10) + ((nt * 16 + lc) << 3)]);
      acc[nt] = __builtin_amdgcn_mfma_f32_16x16x32_bf16(a[kk], bf, acc[nt], 0, 0, 0);
    }
  }

  // epilogue: D[row=q*4+i][col=lc] ; rscale per output row via shuffle
  float rsl[4];
#pragma unroll
  for (int i = 0; i < 4; ++i) rsl[i] = __shfl(rs, q * 4 + i, 64);

#pragma unroll
  for (int nt = 0; nt < 8; ++nt) {
    int j = nt * 16 + lc;
    float bj = bs[j];
#pragma unroll
    for (int i = 0; i < 4; ++i) {
      int gr = r0 + w * 16 + q * 4 + i;
      if (gr < N) h[(size_t)gr * D + j] = f2bf(rsl[i] * acc[nt][i] + bj);
    }
  }
}

// ---------------- gather + expmap0 fused (one wave per dst node) ----------------
__global__ __launch_bounds__(256) void k_gather_expmap(
    const unsigned short* __restrict__ h, const int* __restrict__ ebuf,
    const int* __restrict__ offs, const float* __restrict__ dinv,
    float* __restrict__ out, int N) {
  int gid = blockIdx.x * 256 + threadIdx.x;
  int r = gid >> 6, lane = gid & 63;
  if (r >= N) return;

  int start = offs[r], end = offs[r + 1];
  float di_d = dinv[r];
  float ax = 0.0f, ay = 0.0f;

  int s_next = (start < end) ? ebuf[start] : 0;
  for (int i = start; i < end; ++i) {
    int s = s_next;
    if (i + 1 < end) s_next = ebuf[i + 1];
    float wgt = di_d * dinv[s];
    unsigned int pv = *(const unsigned int*)(h + (size_t)s * D + lane * 2);
    ax += wgt * bf2f(pv & 0xFFFFu);
    ay += wgt * bf2f(pv >> 16);
  }

  float sN = ax * ax + ay * ay;
#pragma unroll
  for (int off = 32; off > 0; off >>= 1) sN += __shfl_down(sN, off, 64);
  sN = __shfl(sN, 0, 64);
  float n = sqrtf(sN);
  float sc = tanhf(n) / fmaxf(n, 1e-15f);

  float2* op = (float2*)(out + (size_t)r * D);
  op[lane] = make_float2(ax * sc, ay * sc);
}

extern "C" void kernel_launch(void* const* d_in, const int* in_sizes, int n_in,
                              void* d_out, int out_size, void* d_ws, size_t ws_size,
                              hipStream_t stream) {
  const float* x = (const float*)d_in[0];
  const int* ei = (const int*)d_in[1];
  const float* W = (const float*)d_in[2];
  const float* b = (const float*)d_in[3];
  float* out = (float*)d_out;

  const int N = in_sizes[0] / D;
  const int E = in_sizes[1] / 2;
  const int* src = ei;
  const int* dst = ei + E;

  // workspace layout
  unsigned short* h = (unsigned short*)d_ws;      // N*D bf16
  float* dinv = (float*)(h + (size_t)N * D);      // N floats
  int* cnt = (int*)(dinv + N);                    // N ints
  int* cnts = cnt + N;                            // N ints (later cursor)
  int* offs = cnts + N;                           // N+1 ints
  int* bsum = offs + N + 1;                       // 256 ints
  int* ebuf = bsum + 256;                         // E ints

  const int nb = (N + 255) / 256;

  hipMemsetAsync(cnt, 0, (size_t)N * sizeof(int) * 2, stream);  // cnt + cnts

  k_hist<<<(E + 255) / 256, 256, 0, stream>>>(src, dst, cnt, cnts, E);
  k_dinv<<<nb, 256, 0, stream>>>(cnt, cnts, dinv, N);
  k_scan1<<<nb, 256, 0, stream>>>(cnt, offs, bsum, N);
  k_scan2<<<1, 256, 0, stream>>>(bsum, nb);
  k_scan3<<<(N + 256) / 256, 256, 0, stream>>>(offs, bsum, N, E);

  hipMemsetAsync(cnts, 0, (size_t)N * sizeof(int), stream);  // cursor
  k_fill<<<(E + 255) / 256, 256, 0, stream>>>(src, dst, offs, cnts, ebuf, E);

  k_gemm_mfma<<<(N + 63) / 64, 256, 0, stream>>>(x, W, b, h, N);

  k_gather_expmap<<<(int)(((long long)N * 64 + 255) / 256), 256, 0, stream>>>(
      h, ebuf, offs, dinv, out, N);
}